// Round 4
// baseline (529.736 us; speedup 1.0000x reference)
//
#include <hip/hip_runtime.h>
#include <hip/hip_fp16.h>

#define HW 4096
#define NC 192
#define NB 8
#define DQK 32   // padded qk depth (24 real + 8 zero)
#define LOG2E 1.4426950408889634f
#define THR 8.0f

typedef _Float16 f16x8 __attribute__((ext_vector_type(8)));
typedef float f32x4 __attribute__((ext_vector_type(4)));
typedef unsigned int u32x2 __attribute__((ext_vector_type(2)));
typedef unsigned int u32x4 __attribute__((ext_vector_type(4)));

static __device__ __forceinline__ unsigned int pkrtz(float a, float b) {
  auto h = __builtin_amdgcn_cvt_pkrtz(a, b);   // native __fp16 ext_vector_type(2)
  return __builtin_bit_cast(unsigned int, h);
}
static __device__ __forceinline__ unsigned short f2h_bits(float f) {
  _Float16 h = (_Float16)f;  // RTE
  union { _Float16 h; unsigned short u; } cv; cv.h = h; return cv.u;
}

// ---------------- weight transpose: wt[c][och] (c-major) + bias row (192) + slope row (193)
__global__ void wtrans_kernel(
    const float* __restrict__ w1, const float* __restrict__ b1, const float* __restrict__ a1,
    const float* __restrict__ w2, const float* __restrict__ b2, const float* __restrict__ a2,
    const float* __restrict__ wa, const float* __restrict__ ba, const float* __restrict__ aa,
    float* __restrict__ wt)
{
  const int c = blockIdx.x;     // 0..193
  const int o = threadIdx.x;    // 0..255
  if (o >= 240) return;
  float v;
  if (c < 192) {
    if (o < 24)      v = w1[o * 192 + c];
    else if (o < 48) v = w2[(o - 24) * 192 + c];
    else             v = wa[(o - 48) * 192 + c];
  } else if (c == 192) {
    v = (o < 24) ? b1[o] : (o < 48) ? b2[o - 24] : ba[o - 48];
  } else {
    v = (o < 24) ? a1[0] : (o < 48) ? a2[0] : aa[0];
  }
  wt[c * 240 + o] = v;
}

// ---------------- projection: thread = 2 positions x 16 out-channels, weights via scalar loads
__global__ __launch_bounds__(256) void proj_kernel(
    const float* __restrict__ x, const float* __restrict__ wt,
    unsigned short* __restrict__ Qn, unsigned short* __restrict__ Kn,
    unsigned short* __restrict__ Vt)
{
  const int g   = blockIdx.y;                       // 16-channel group 0..14
  const int tid = threadIdx.x;
  const int bp  = (blockIdx.x * 256 + tid) * 2;     // first of 2 positions
  const int b   = bp >> 12;                         // uniform per block (512 | 4096)
  const int pos = bp & (HW - 1);

  const float* xb = x + (size_t)b * NC * HW + pos;
  float acc0[16], acc1[16];
  #pragma unroll
  for (int o = 0; o < 16; ++o) { acc0[o] = 0.f; acc1[o] = 0.f; }

  #pragma unroll 4
  for (int c = 0; c < 192; ++c) {
    float2 xv = *reinterpret_cast<const float2*>(xb + (size_t)c * HW);
    const float* wr = wt + c * 240 + g * 16;        // wave-uniform address -> s_load
    #pragma unroll
    for (int o = 0; o < 16; ++o) {
      float w = wr[o];
      acc0[o] = fmaf(w, xv.x, acc0[o]);
      acc1[o] = fmaf(w, xv.y, acc1[o]);
    }
  }

  const float* brow = wt + 192 * 240 + g * 16;
  const float* srow = wt + 193 * 240 + g * 16;
  unsigned short h0[16], h1[16];
  #pragma unroll
  for (int o = 0; o < 16; ++o) {
    float bias = brow[o], sm1 = srow[o] - 1.f;
    float v0 = acc0[o] + bias; v0 += fminf(v0, 0.f) * sm1;
    float v1 = acc1[o] + bias; v1 += fminf(v1, 0.f) * sm1;
    h0[o] = f2h_bits(v0);
    h1[o] = f2h_bits(v1);
  }

  if (g >= 3) {
    // v channels: pack the 2 consecutive positions into one u32 store per channel
    const int vch0 = g * 16 - 48;
    unsigned int* vp = reinterpret_cast<unsigned int*>(
        Vt + ((size_t)b * NC + vch0) * HW + pos);
    #pragma unroll
    for (int o = 0; o < 16; ++o)
      vp[o * (HW / 2)] = (unsigned int)h0[o] | ((unsigned int)h1[o] << 16);
  } else {
    // pack 16 halves (channel-major) into 4+4 u32 per position
    u32x4 lo0, hi0, lo1, hi1;
    #pragma unroll
    for (int j = 0; j < 4; ++j) {
      lo0[j] = (unsigned int)h0[2 * j] | ((unsigned int)h0[2 * j + 1] << 16);
      hi0[j] = (unsigned int)h0[8 + 2 * j] | ((unsigned int)h0[9 + 2 * j] << 16);
      lo1[j] = (unsigned int)h1[2 * j] | ((unsigned int)h1[2 * j + 1] << 16);
      hi1[j] = (unsigned int)h1[8 + 2 * j] | ((unsigned int)h1[9 + 2 * j] << 16);
    }
    const size_t bpos = (size_t)b * HW + pos;
    if (g == 0) {           // q channels 0..15
      u32x4* q0 = reinterpret_cast<u32x4*>(Qn + bpos * DQK);
      q0[0] = lo0; q0[1] = hi0;
      u32x4* q1 = reinterpret_cast<u32x4*>(Qn + (bpos + 1) * DQK);
      q1[0] = lo1; q1[1] = hi1;
    } else if (g == 1) {    // q 16..23 (lo), k 0..7 (hi)
      *reinterpret_cast<u32x4*>(Qn + bpos * DQK + 16) = lo0;
      *reinterpret_cast<u32x4*>(Kn + bpos * DQK) = hi0;
      *reinterpret_cast<u32x4*>(Qn + (bpos + 1) * DQK + 16) = lo1;
      *reinterpret_cast<u32x4*>(Kn + (bpos + 1) * DQK) = hi1;
    } else {                // k 8..23
      u32x4* k0 = reinterpret_cast<u32x4*>(Kn + bpos * DQK + 8);
      k0[0] = lo0; k0[1] = hi0;
      u32x4* k1 = reinterpret_cast<u32x4*>(Kn + (bpos + 1) * DQK + 8);
      k1[0] = lo1; k1[1] = hi1;
    }
  }
}

// ---------------- flash attention, swapped-QK^T, wave-private, no barriers
__global__ __launch_bounds__(256) void flash_kernel(
    const unsigned short* __restrict__ Qn, const unsigned short* __restrict__ Kn,
    const unsigned short* __restrict__ Vt, float* __restrict__ out)
{
  const int b    = blockIdx.y;
  const int tid  = threadIdx.x;
  const int wv   = tid >> 6;
  const int lane = tid & 63;
  const int lq   = lane & 15;    // this lane's q-row (within wave tile) in softmax phase
  const int lk   = lane >> 4;
  const int qrow0 = blockIdx.x * 64 + wv * 16;

  __shared__ __align__(16) unsigned char Pbuf[4][2048];
  unsigned char* myP = &Pbuf[wv][0];
  const int swz = (lq & 7) << 4;
  const int rowbase = lq * 128;
  int wb[4], rb[2];
  #pragma unroll
  for (int t = 0; t < 4; ++t)  wb[t] = rowbase + (((t << 5) | (lk << 3)) ^ swz);
  #pragma unroll
  for (int kk = 0; kk < 2; ++kk) rb[kk] = rowbase + (((kk << 6) | (lk << 4)) ^ swz);

  f16x8 qfrag = *reinterpret_cast<const f16x8*>(
      Qn + ((size_t)b * HW + qrow0 + lq) * DQK + 8 * lk);

  float m = -1e30f, l = 0.f;
  f32x4 O[12];
  #pragma unroll
  for (int tc = 0; tc < 12; ++tc) O[tc] = (f32x4){0.f, 0.f, 0.f, 0.f};

  const unsigned short* Kb = Kn + (size_t)b * HW * DQK;
  const unsigned short* Vb = Vt + (size_t)b * NC * HW;

  for (int m0 = 0; m0 < HW; m0 += 64) {
    // ---- S^T tiles: lane holds P[q=lq][m = 16t + 4lk + r]
    f32x4 s[4];
    #pragma unroll
    for (int t = 0; t < 4; ++t) {
      f16x8 kf = *reinterpret_cast<const f16x8*>(
          Kb + (size_t)(m0 + t * 16 + lq) * DQK + 8 * lk);
      s[t] = __builtin_amdgcn_mfma_f32_16x16x32_f16(kf, qfrag,
              (f32x4){0.f, 0.f, 0.f, 0.f}, 0, 0, 0);
    }
    // ---- row max: 15 local fmax + 2 shfl
    float pmax = s[0][0];
    #pragma unroll
    for (int t = 0; t < 4; ++t)
      #pragma unroll
      for (int r = 0; r < 4; ++r) pmax = fmaxf(pmax, s[t][r]);
    pmax = fmaxf(pmax, __shfl_xor(pmax, 16));
    pmax = fmaxf(pmax, __shfl_xor(pmax, 32));
    // ---- deferred rescale (rare after first iter)
    if (__any(pmax > m + THR)) {
      float mnew  = fmaxf(m, pmax);
      float alpha = __expf(m - mnew);
      m = mnew;
      l *= alpha;
      float a0 = __shfl(alpha, lk * 4 + 0), a1 = __shfl(alpha, lk * 4 + 1);
      float a2 = __shfl(alpha, lk * 4 + 2), a3 = __shfl(alpha, lk * 4 + 3);
      #pragma unroll
      for (int tc = 0; tc < 12; ++tc) {
        O[tc][0] *= a0; O[tc][1] *= a1; O[tc][2] *= a2; O[tc][3] *= a3;
      }
    }
    // ---- P = exp(S - m), row sum, pack to f16
    const float mm = m * LOG2E;
    float psum = 0.f;
    u32x2 u[4];
    #pragma unroll
    for (int t = 0; t < 4; ++t) {
      f32x4 p;
      #pragma unroll
      for (int r = 0; r < 4; ++r) {
        p[r] = exp2f(fmaf(s[t][r], LOG2E, -mm));
        psum += p[r];
      }
      u[t].x = pkrtz(p[0], p[1]);
      u[t].y = pkrtz(p[2], p[3]);
    }
    psum += __shfl_xor(psum, 16);
    psum += __shfl_xor(psum, 32);
    l += psum;
    // ---- wave-private LDS redistribution (swizzled, conflict-free, no barrier)
    #pragma unroll
    for (int t = 0; t < 4; ++t)
      *reinterpret_cast<u32x2*>(myP + wb[t]) = u[t];
    f16x8 pa0 = *reinterpret_cast<const f16x8*>(myP + rb[0]);
    f16x8 pa1 = *reinterpret_cast<const f16x8*>(myP + rb[1]);
    // ---- O += P V^T over all 192 channels
    #pragma unroll
    for (int kk = 0; kk < 2; ++kk) {
      f16x8 pa = kk ? pa1 : pa0;
      #pragma unroll
      for (int tc = 0; tc < 12; ++tc) {
        f16x8 vb = *reinterpret_cast<const f16x8*>(
            Vb + (size_t)(tc * 16 + lq) * HW + m0 + kk * 32 + 8 * lk);
        O[tc] = __builtin_amdgcn_mfma_f32_16x16x32_f16(pa, vb, O[tc], 0, 0, 0);
      }
    }
  }

  // ---- normalize and store (coalesced dwordx4: q-offset 4*lk+r contiguous)
  float l0 = __shfl(l, lk * 4 + 0), l1 = __shfl(l, lk * 4 + 1);
  float l2 = __shfl(l, lk * 4 + 2), l3 = __shfl(l, lk * 4 + 3);
  f32x4 inv = {1.f / l0, 1.f / l1, 1.f / l2, 1.f / l3};
  #pragma unroll
  for (int tc = 0; tc < 12; ++tc) {
    f32x4 o4;
    o4[0] = O[tc][0] * inv[0]; o4[1] = O[tc][1] * inv[1];
    o4[2] = O[tc][2] * inv[2]; o4[3] = O[tc][3] * inv[3];
    *reinterpret_cast<f32x4*>(
        out + ((size_t)b * NC + tc * 16 + lq) * HW + qrow0 + lk * 4) = o4;
  }
}

extern "C" void kernel_launch(void* const* d_in, const int* in_sizes, int n_in,
                              void* d_out, int out_size, void* d_ws, size_t ws_size,
                              hipStream_t stream) {
  const float* x  = (const float*)d_in[0];
  const float* w1 = (const float*)d_in[1];
  const float* b1 = (const float*)d_in[2];
  const float* a1 = (const float*)d_in[3];
  const float* w2 = (const float*)d_in[4];
  const float* b2 = (const float*)d_in[5];
  const float* a2 = (const float*)d_in[6];
  const float* wa = (const float*)d_in[7];
  const float* ba = (const float*)d_in[8];
  const float* aa = (const float*)d_in[9];
  float* out = (float*)d_out;

  unsigned short* Qn = (unsigned short*)d_ws;                 // 2 MB
  unsigned short* Kn = Qn + (size_t)NB * HW * DQK;            // 2 MB
  unsigned short* Vt = Kn + (size_t)NB * HW * DQK;            // 12 MB
  // transposed weights live in the tail of d_out (overwritten by flash_kernel later)
  float* wt = out + (out_size - 49152);                       // 194*240 = 46560 floats used

  // zero Q+K (covers d=24..31 padding)
  (void)hipMemsetAsync(Qn, 0, (size_t)NB * HW * DQK * 2 * sizeof(unsigned short), stream);

  wtrans_kernel<<<dim3(194), 256, 0, stream>>>(w1, b1, a1, w2, b2, a2, wa, ba, aa, wt);

  dim3 pgrid(HW * NB / 512, 15);
  proj_kernel<<<pgrid, 256, 0, stream>>>(x, wt, Qn, Kn, Vt);

  dim3 fgrid(HW / 64, NB);
  flash_kernel<<<fgrid, 256, 0, stream>>>(Qn, Kn, Vt, out);
}

// Round 5
// 205.132 us; speedup vs baseline: 2.5824x; 2.5824x over previous
//
#include <hip/hip_runtime.h>
#include <hip/hip_fp16.h>

#define HW 4096
#define NC 192
#define NB 8
#define DQK 32   // padded qk depth (24 real + 8 zero)
#define LOG2E 1.4426950408889634f
#define THR 8.0f

typedef _Float16 f16x8 __attribute__((ext_vector_type(8)));
typedef float f32x4 __attribute__((ext_vector_type(4)));
typedef unsigned int u32x4 __attribute__((ext_vector_type(4)));

static __device__ __forceinline__ unsigned int pkrtz(float a, float b) {
  auto h = __builtin_amdgcn_cvt_pkrtz(a, b);   // native __fp16 ext_vector_type(2)
  return __builtin_bit_cast(unsigned int, h);
}
static __device__ __forceinline__ unsigned short f2h_bits(float f) {
  _Float16 h = (_Float16)f;  // RTE
  union { _Float16 h; unsigned short u; } cv; cv.h = h; return cv.u;
}

// ---------------- weight transpose: wt[c][och] (c-major) + bias row (192) + slope row (193)
__global__ void wtrans_kernel(
    const float* __restrict__ w1, const float* __restrict__ b1, const float* __restrict__ a1,
    const float* __restrict__ w2, const float* __restrict__ b2, const float* __restrict__ a2,
    const float* __restrict__ wa, const float* __restrict__ ba, const float* __restrict__ aa,
    float* __restrict__ wt)
{
  const int c = blockIdx.x;     // 0..193
  const int o = threadIdx.x;    // 0..255
  if (o >= 240) return;
  float v;
  if (c < 192) {
    if (o < 24)      v = w1[o * 192 + c];
    else if (o < 48) v = w2[(o - 24) * 192 + c];
    else             v = wa[(o - 48) * 192 + c];
  } else if (c == 192) {
    v = (o < 24) ? b1[o] : (o < 48) ? b2[o - 24] : ba[o - 48];
  } else {
    v = (o < 24) ? a1[0] : (o < 48) ? a2[0] : aa[0];
  }
  wt[c * 240 + o] = v;
}

// ---------------- projection: thread = 2 positions x 16 out-channels, weights via scalar loads
__global__ __launch_bounds__(256) void proj_kernel(
    const float* __restrict__ x, const float* __restrict__ wt,
    unsigned short* __restrict__ Qn, unsigned short* __restrict__ Kn,
    unsigned short* __restrict__ Vt)
{
  const int g   = blockIdx.y;                       // 16-channel group 0..14
  const int tid = threadIdx.x;
  const int bp  = (blockIdx.x * 256 + tid) * 2;     // first of 2 positions
  const int b   = bp >> 12;                         // uniform per block (512 | 4096)
  const int pos = bp & (HW - 1);

  const float* xb = x + (size_t)b * NC * HW + pos;
  float acc0[16], acc1[16];
  #pragma unroll
  for (int o = 0; o < 16; ++o) { acc0[o] = 0.f; acc1[o] = 0.f; }

  #pragma unroll 4
  for (int c = 0; c < 192; ++c) {
    float2 xv = *reinterpret_cast<const float2*>(xb + (size_t)c * HW);
    const float* wr = wt + c * 240 + g * 16;        // wave-uniform address -> s_load
    #pragma unroll
    for (int o = 0; o < 16; ++o) {
      float w = wr[o];
      acc0[o] = fmaf(w, xv.x, acc0[o]);
      acc1[o] = fmaf(w, xv.y, acc1[o]);
    }
  }

  const float* brow = wt + 192 * 240 + g * 16;
  const float* srow = wt + 193 * 240 + g * 16;
  unsigned short h0[16], h1[16];
  #pragma unroll
  for (int o = 0; o < 16; ++o) {
    float bias = brow[o], sm1 = srow[o] - 1.f;
    float v0 = acc0[o] + bias; v0 += fminf(v0, 0.f) * sm1;
    float v1 = acc1[o] + bias; v1 += fminf(v1, 0.f) * sm1;
    h0[o] = f2h_bits(v0);
    h1[o] = f2h_bits(v1);
  }

  if (g >= 3) {
    const int vch0 = g * 16 - 48;
    unsigned int* vp = reinterpret_cast<unsigned int*>(
        Vt + ((size_t)b * NC + vch0) * HW + pos);
    #pragma unroll
    for (int o = 0; o < 16; ++o)
      vp[o * (HW / 2)] = (unsigned int)h0[o] | ((unsigned int)h1[o] << 16);
  } else {
    u32x4 lo0, hi0, lo1, hi1;
    #pragma unroll
    for (int j = 0; j < 4; ++j) {
      lo0[j] = (unsigned int)h0[2 * j] | ((unsigned int)h0[2 * j + 1] << 16);
      hi0[j] = (unsigned int)h0[8 + 2 * j] | ((unsigned int)h0[9 + 2 * j] << 16);
      lo1[j] = (unsigned int)h1[2 * j] | ((unsigned int)h1[2 * j + 1] << 16);
      hi1[j] = (unsigned int)h1[8 + 2 * j] | ((unsigned int)h1[9 + 2 * j] << 16);
    }
    const size_t bpos = (size_t)b * HW + pos;
    if (g == 0) {
      u32x4* q0 = reinterpret_cast<u32x4*>(Qn + bpos * DQK);
      q0[0] = lo0; q0[1] = hi0;
      u32x4* q1 = reinterpret_cast<u32x4*>(Qn + (bpos + 1) * DQK);
      q1[0] = lo1; q1[1] = hi1;
    } else if (g == 1) {
      *reinterpret_cast<u32x4*>(Qn + bpos * DQK + 16) = lo0;
      *reinterpret_cast<u32x4*>(Kn + bpos * DQK) = hi0;
      *reinterpret_cast<u32x4*>(Qn + (bpos + 1) * DQK + 16) = lo1;
      *reinterpret_cast<u32x4*>(Kn + (bpos + 1) * DQK) = hi1;
    } else {
      u32x4* k0 = reinterpret_cast<u32x4*>(Kn + bpos * DQK + 8);
      k0[0] = lo0; k0[1] = hi0;
      u32x4* k1 = reinterpret_cast<u32x4*>(Kn + (bpos + 1) * DQK + 8);
      k1[0] = lo1; k1[1] = hi1;
    }
  }
}

// ---------------- flash attention: 8 waves = 2 m-halves x 4 groups
// wave (h, wi): softmax owner of q-tile wi (rows q0+16wi..+15) for m in half h,
//               PV owner of channels wi*48..wi*48+47 for ALL 64 q-rows, half h.
// sigma-permuted K loads leave P in PV A-fragment register order (no shuffle).
__global__ __launch_bounds__(512, 4) void flash_kernel(
    const unsigned short* __restrict__ Qn, const unsigned short* __restrict__ Kn,
    const unsigned short* __restrict__ Vt, float* __restrict__ out)
{
  const int b    = blockIdx.y;
  const int q0   = blockIdx.x * 64;
  const int tid  = threadIdx.x;
  const int w    = tid >> 6;
  const int half = w >> 2;
  const int wi   = w & 3;
  const int lane = tid & 63;
  const int lq   = lane & 15;
  const int lk   = lane >> 4;

  __shared__ u32x4 Pex[2][4][2][64];     // 16 KB  [half][qtile][kk][lane] A-fragments
  __shared__ float alphaL[2][4][16];     // 512 B  [half][qtile][row]
  __shared__ float mlL[2][2][64];        // 1 KB   [half][{m,l}][qrow]
  __shared__ f32x4 Obuf[4][64][13];      // 53 KB  [group][lane][tile(12)+pad]

  const int mbase = half * (HW / 2);
  const int sigb  = 8 * (lq >> 2) + (lq & 3);   // sigma permutation base

  f16x8 qfrag = *reinterpret_cast<const f16x8*>(
      Qn + ((size_t)b * HW + q0 + 16 * wi + lq) * DQK + 8 * lk);

  float m = -1e30f, l = 0.f;
  f32x4 O[12];
  #pragma unroll
  for (int i = 0; i < 12; ++i) O[i] = (f32x4){0.f, 0.f, 0.f, 0.f};

  const unsigned short* Kb = Kn + (size_t)b * HW * DQK;
  const unsigned short* Vb = Vt + (size_t)b * NC * HW;

  for (int it = 0; it < HW / 2 / 64; ++it) {
    const int m0 = mbase + it * 64;
    // ---- QK^T with sigma-permuted rows: s[t][r] = S[m = sigb(lq).. ][q=lq]
    f32x4 s[4];
    #pragma unroll
    for (int t = 0; t < 4; ++t) {
      const int mo = m0 + sigb + 32 * (t & 1) + 4 * (t >> 1);
      f16x8 kf = *reinterpret_cast<const f16x8*>(Kb + (size_t)mo * DQK + 8 * lk);
      s[t] = __builtin_amdgcn_mfma_f32_16x16x32_f16(kf, qfrag,
              (f32x4){0.f, 0.f, 0.f, 0.f}, 0, 0, 0);
    }
    // ---- row max (lane holds 16 vals of row lq; reduce over lanes lq, lq+16, ...)
    float pmax = s[0][0];
    #pragma unroll
    for (int t = 0; t < 4; ++t)
      #pragma unroll
      for (int r = 0; r < 4; ++r) pmax = fmaxf(pmax, s[t][r]);
    pmax = fmaxf(pmax, __shfl_xor(pmax, 16));
    pmax = fmaxf(pmax, __shfl_xor(pmax, 32));
    // ---- deferred rescale
    float alpha = 1.f;
    if (__any(pmax > m + THR)) {
      float mnew = fmaxf(m, pmax);
      alpha = __expf(m - mnew);
      m = mnew;
      l *= alpha;
    }
    if (lane < 16) alphaL[half][wi][lq] = alpha;
    // ---- P = exp(S - m), sum, pack into PV A-fragments (register-resident)
    const float mm = m * LOG2E;
    float psum = 0.f;
    f32x4 p[4];
    #pragma unroll
    for (int t = 0; t < 4; ++t)
      #pragma unroll
      for (int r = 0; r < 4; ++r) {
        p[t][r] = exp2f(fmaf(s[t][r], LOG2E, -mm));
        psum += p[t][r];
      }
    psum += __shfl_xor(psum, 16);
    psum += __shfl_xor(psum, 32);
    l += psum;
    u32x4 pa0, pa1;
    pa0[0] = pkrtz(p[0][0], p[0][1]); pa0[1] = pkrtz(p[0][2], p[0][3]);
    pa0[2] = pkrtz(p[2][0], p[2][1]); pa0[3] = pkrtz(p[2][2], p[2][3]);
    pa1[0] = pkrtz(p[1][0], p[1][1]); pa1[1] = pkrtz(p[1][2], p[1][3]);
    pa1[2] = pkrtz(p[3][0], p[3][1]); pa1[3] = pkrtz(p[3][2], p[3][3]);
    Pex[half][wi][0][lane] = pa0;
    Pex[half][wi][1][lane] = pa1;
    __syncthreads();
    // ---- rescale O where needed (alphas broadcast from LDS, branch wave-uniform)
    #pragma unroll
    for (int tr = 0; tr < 4; ++tr) {
      f32x4 al = *reinterpret_cast<const f32x4*>(&alphaL[half][tr][4 * lk]);
      int diff = (al[0] != 1.f) | (al[1] != 1.f) | (al[2] != 1.f) | (al[3] != 1.f);
      if (__any(diff)) {
        #pragma unroll
        for (int tc = 0; tc < 3; ++tc) {
          O[tr * 3 + tc][0] *= al[0]; O[tr * 3 + tc][1] *= al[1];
          O[tr * 3 + tc][2] *= al[2]; O[tr * 3 + tc][3] *= al[3];
        }
      }
    }
    // ---- O += P V  (wave's 48 channels, all 4 q-tiles)
    #pragma unroll
    for (int kk = 0; kk < 2; ++kk) {
      f16x8 paf[4];
      #pragma unroll
      for (int tr = 0; tr < 4; ++tr)
        paf[tr] = __builtin_bit_cast(f16x8, Pex[half][tr][kk][lane]);
      #pragma unroll
      for (int tc = 0; tc < 3; ++tc) {
        f16x8 vb = *reinterpret_cast<const f16x8*>(
            Vb + (size_t)(wi * 48 + tc * 16 + lq) * HW + m0 + kk * 32 + 8 * lk);
        #pragma unroll
        for (int tr = 0; tr < 4; ++tr)
          O[tr * 3 + tc] = __builtin_amdgcn_mfma_f32_16x16x32_f16(paf[tr], vb,
                               O[tr * 3 + tc], 0, 0, 0);
      }
    }
    __syncthreads();
  }

  // ---- cross-half combine: half1 parks O in LDS; half0 merges + stores
  if (lane < 16) {
    mlL[half][0][16 * wi + lq] = m;
    mlL[half][1][16 * wi + lq] = l;
  }
  if (half == 1) {
    #pragma unroll
    for (int i = 0; i < 12; ++i) Obuf[wi][lane][i] = O[i];
  }
  __syncthreads();
  if (half == 0) {
    #pragma unroll
    for (int tr = 0; tr < 4; ++tr) {
      f32x4 m0v = *reinterpret_cast<const f32x4*>(&mlL[0][0][16 * tr + 4 * lk]);
      f32x4 l0v = *reinterpret_cast<const f32x4*>(&mlL[0][1][16 * tr + 4 * lk]);
      f32x4 m1v = *reinterpret_cast<const f32x4*>(&mlL[1][0][16 * tr + 4 * lk]);
      f32x4 l1v = *reinterpret_cast<const f32x4*>(&mlL[1][1][16 * tr + 4 * lk]);
      f32x4 f0, f1;
      #pragma unroll
      for (int r = 0; r < 4; ++r) {
        float M  = fmaxf(m0v[r], m1v[r]);
        float s0 = __expf(m0v[r] - M), s1 = __expf(m1v[r] - M);
        float L  = s0 * l0v[r] + s1 * l1v[r];
        f0[r] = s0 / L; f1[r] = s1 / L;
      }
      #pragma unroll
      for (int tc = 0; tc < 3; ++tc) {
        f32x4 o1 = Obuf[wi][lane][tr * 3 + tc];
        f32x4 o;
        #pragma unroll
        for (int r = 0; r < 4; ++r)
          o[r] = O[tr * 3 + tc][r] * f0[r] + o1[r] * f1[r];
        *reinterpret_cast<f32x4*>(
            out + ((size_t)b * NC + wi * 48 + tc * 16 + lq) * HW + q0 + 16 * tr + 4 * lk) = o;
      }
    }
  }
}

extern "C" void kernel_launch(void* const* d_in, const int* in_sizes, int n_in,
                              void* d_out, int out_size, void* d_ws, size_t ws_size,
                              hipStream_t stream) {
  const float* x  = (const float*)d_in[0];
  const float* w1 = (const float*)d_in[1];
  const float* b1 = (const float*)d_in[2];
  const float* a1 = (const float*)d_in[3];
  const float* w2 = (const float*)d_in[4];
  const float* b2 = (const float*)d_in[5];
  const float* a2 = (const float*)d_in[6];
  const float* wa = (const float*)d_in[7];
  const float* ba = (const float*)d_in[8];
  const float* aa = (const float*)d_in[9];
  float* out = (float*)d_out;

  unsigned short* Qn = (unsigned short*)d_ws;                 // 2 MB
  unsigned short* Kn = Qn + (size_t)NB * HW * DQK;            // 2 MB
  unsigned short* Vt = Kn + (size_t)NB * HW * DQK;            // 12 MB
  float* wt = out + (out_size - 49152);                       // 194*240 floats used

  (void)hipMemsetAsync(Qn, 0, (size_t)NB * HW * DQK * 2 * sizeof(unsigned short), stream);

  wtrans_kernel<<<dim3(194), 256, 0, stream>>>(w1, b1, a1, w2, b2, a2, wa, ba, aa, wt);

  dim3 pgrid(HW * NB / 512, 15);
  proj_kernel<<<pgrid, 256, 0, stream>>>(x, wt, Qn, Kn, Vt);

  dim3 fgrid(HW / 64, NB);
  flash_kernel<<<fgrid, 512, 0, stream>>>(Qn, Kn, Vt, out);
}